// Round 4
// baseline (207.150 us; speedup 1.0000x reference)
//
#include <hip/hip_runtime.h>
#include <hip/hip_bf16.h>
#include <math.h>

#define DMODEL 1024
#define NHEADS 16
#define DKH    64
#define BATCH  2
#define SEQ    2048
#define MROWS  (BATCH * SEQ)   // 4096
#define LOG2E  1.4426950408889634f

typedef __bf16 bf16_t;
typedef bf16_t bf16x8 __attribute__((ext_vector_type(8)));
typedef bf16_t bf16x4 __attribute__((ext_vector_type(4)));
typedef float  floatx4 __attribute__((ext_vector_type(4)));

// async global->LDS, 16B per lane
__device__ __forceinline__ void glds16(const bf16_t* g, bf16_t* l) {
    __builtin_amdgcn_global_load_lds((__attribute__((address_space(1))) unsigned*)(g),
                                     (__attribute__((address_space(3))) unsigned*)(l),
                                     16, 0, 0);
}

// ---------------------------------------------------------------- cast x -> bf16
__global__ void cast_x_kernel(const float* __restrict__ x, bf16_t* __restrict__ xb) {
    int i = (blockIdx.x * 256 + threadIdx.x) * 4;
    float4 v = *(const float4*)(x + i);
    bf16_t o0 = (bf16_t)v.x, o1 = (bf16_t)v.y, o2 = (bf16_t)v.z, o3 = (bf16_t)v.w;
    bf16_t o[4] = {o0, o1, o2, o3};
    *(uint2*)(xb + i) = *(uint2*)o;
}

// --------------------------- 4x W (K x N) -> W^T (N x K) bf16, fused over z
__global__ void transpose4_kernel(const float* __restrict__ W0, const float* __restrict__ W1,
                                  const float* __restrict__ W2, const float* __restrict__ W3,
                                  bf16_t* __restrict__ Wt) {
    __shared__ float t[32][33];
    const float* W = (blockIdx.z == 0) ? W0 : (blockIdx.z == 1) ? W1 : (blockIdx.z == 2) ? W2 : W3;
    bf16_t* dst = Wt + (size_t)blockIdx.z * DMODEL * DMODEL;
    int bx = blockIdx.x, by = blockIdx.y;
    int tx = threadIdx.x, ty = threadIdx.y;
#pragma unroll
    for (int i = 0; i < 32; i += 8)
        t[ty + i][tx] = W[(size_t)(by * 32 + ty + i) * DMODEL + bx * 32 + tx];
    __syncthreads();
#pragma unroll
    for (int i = 0; i < 32; i += 8)
        dst[(size_t)(bx * 32 + ty + i) * DMODEL + by * 32 + tx] = (bf16_t)t[tx][ty + i];
}

// ---------------------------------------------------------------- 128x128 GEMM, BK=64
template<int MODE>
__global__ __launch_bounds__(256) void gemm128_kernel(const bf16_t* __restrict__ A,
                                                      const bf16_t* __restrict__ Bt,
                                                      void* __restrict__ outp) {
    __shared__ bf16_t As[128 * 64];
    __shared__ bf16_t Bs[128 * 64];
    int tid = threadIdx.x;
    int w = tid >> 6, l = tid & 63, g = l >> 4, lm = l & 15;
    int wr = w >> 1, wc = w & 1;
    int m0 = blockIdx.y * 128, n0 = blockIdx.x * 128;
    int r8 = l >> 3, s8 = l & 7, cw = s8 ^ r8;

    floatx4 acc[4][4];
#pragma unroll
    for (int i = 0; i < 4; ++i)
#pragma unroll
        for (int j = 0; j < 4; ++j) { floatx4 z = {0.f, 0.f, 0.f, 0.f}; acc[i][j] = z; }

    const bf16_t* Ag = A  + (size_t)(m0 + w * 32 + r8) * DMODEL + cw * 8;
    const bf16_t* Bg = Bt + (size_t)(n0 + w * 32 + r8) * DMODEL + cw * 8;

    for (int k0 = 0; k0 < DMODEL; k0 += 64) {
        __syncthreads();
#pragma unroll
        for (int j = 0; j < 4; ++j) {
            glds16(Ag + (size_t)j * 8 * DMODEL + k0, &As[(w * 32 + j * 8) * 64]);
            glds16(Bg + (size_t)j * 8 * DMODEL + k0, &Bs[(w * 32 + j * 8) * 64]);
        }
        __syncthreads();
#pragma unroll
        for (int kk = 0; kk < 2; ++kk) {
            bf16x8 af[4], bfr[4];
            int c = kk * 4 + g;
            int sw = (c ^ (lm & 7)) * 8;
#pragma unroll
            for (int i = 0; i < 4; ++i) {
                af[i]  = *(const bf16x8*)&As[(wr * 64 + i * 16 + lm) * 64 + sw];
                bfr[i] = *(const bf16x8*)&Bs[(wc * 64 + i * 16 + lm) * 64 + sw];
            }
#pragma unroll
            for (int i = 0; i < 4; ++i)
#pragma unroll
                for (int j = 0; j < 4; ++j)
                    acc[i][j] = __builtin_amdgcn_mfma_f32_16x16x32_bf16(af[i], bfr[j], acc[i][j], 0, 0, 0);
        }
    }

    const size_t NX = (size_t)MROWS * DMODEL;
#pragma unroll
    for (int i = 0; i < 4; ++i) {
#pragma unroll
        for (int j = 0; j < 4; ++j) {
            int nc = n0 + wc * 64 + j * 16 + lm;
            int mb = m0 + wr * 64 + i * 16 + g * 4;
            if (MODE == 0) {
                int mat = n0 >> 10;
                int col = nc & 1023;
                int b = mb >> 11, hh = col >> 6, d = col & 63;
                bf16_t* base = (bf16_t*)outp;
                if (mat == 2) {
                    int s = mb & 2047;
                    bf16x4 pk = {(bf16_t)acc[i][j][0], (bf16_t)acc[i][j][1],
                                 (bf16_t)acc[i][j][2], (bf16_t)acc[i][j][3]};
                    *(bf16x4*)&(base + 2 * NX)[(((size_t)(b * NHEADS + hh)) * DKH + d) * SEQ + s] = pk;
                } else {
#pragma unroll
                    for (int r = 0; r < 4; ++r) {
                        float v = acc[i][j][r];
                        int s = (mb + r) & 2047;
                        if (mat == 0)
                            base[(((size_t)(b * NHEADS + hh)) * SEQ + s) * DKH + d] = (bf16_t)(v * (0.125f * LOG2E));
                        else
                            (base + NX)[(((size_t)(b * NHEADS + hh)) * SEQ + s) * DKH + d] = (bf16_t)v;
                    }
                }
            } else {
#pragma unroll
                for (int r = 0; r < 4; ++r)
                    ((float*)outp)[(size_t)(mb + r) * DMODEL + nc] = acc[i][j][r];
            }
        }
    }
}

// ---------------------------------------------------------------- fused flash attention
// grid (32 bh, 16 qblk), block 256 = 4 waves = 2 q-groups x 2 key-splits.
// Wave: 64 q rows x 1024 keys (16 kt iters). K/V read global->VGPR as MFMA A-frags
// (no LDS staging, no barriers in loop). P round-trips wave-private LDS.
// lsum via ones-MFMA. Key-split partials merged through LDS at the end.
__global__ __launch_bounds__(256, 2) void attn_kernel(const bf16_t* __restrict__ Q,
                                                      const bf16_t* __restrict__ K,
                                                      const bf16_t* __restrict__ Vt,
                                                      bf16_t* __restrict__ Cc) {
    __shared__ bf16_t Ps[4][64 * 64];     // per-wave P^T tile [q][key], swizzled
    __shared__ float  Ms[2][64 * 36];     // merge: [qgroup][q][36] (32 d + lsum @32)

    int tid = threadIdx.x;
    int w = tid >> 6, l = tid & 63, g = l >> 4, lm = l & 15;
    int qw = w & 1, ks = w >> 1;
    int bh = blockIdx.x, b = bh >> 4, h = bh & 15;
    int q0 = blockIdx.y * 128 + qw * 64;
    int xsw = lm & 14;

    const bf16_t* Qh  = Q  + ((size_t)bh * SEQ + q0) * DKH;
    const bf16_t* Kh  = K  + (size_t)bh * SEQ * DKH;
    const bf16_t* Vth = Vt + (size_t)bh * DKH * SEQ;

    // Q as B-frags (loaded once)
    bf16x8 qf[4][2];
#pragma unroll
    for (int nt = 0; nt < 4; ++nt)
#pragma unroll
        for (int kk = 0; kk < 2; ++kk)
            qf[nt][kk] = *(const bf16x8*)(Qh + (size_t)(nt * 16 + lm) * DKH + kk * 32 + g * 8);

    bf16x8 onesf;
#pragma unroll
    for (int j = 0; j < 8; ++j) onesf[j] = (bf16_t)1.0f;

    floatx4 oacc[4][4];
#pragma unroll
    for (int dt = 0; dt < 4; ++dt)
#pragma unroll
        for (int nt = 0; nt < 4; ++nt) { floatx4 z = {0.f, 0.f, 0.f, 0.f}; oacc[dt][nt] = z; }
    floatx4 lacc[4];
#pragma unroll
    for (int nt = 0; nt < 4; ++nt) { floatx4 z = {0.f, 0.f, 0.f, 0.f}; lacc[nt] = z; }

    for (int kt = ks * 16; kt < ks * 16 + 16; ++kt) {
        const bf16_t* Kt  = Kh  + (size_t)kt * 64 * DKH;
        const bf16_t* Vtt = Vth + kt * 64;

        // K tile as A-frags, straight from global (L2-resident)
        bf16x8 kf[4][2];
#pragma unroll
        for (int mt = 0; mt < 4; ++mt)
#pragma unroll
            for (int kk = 0; kk < 2; ++kk)
                kf[mt][kk] = *(const bf16x8*)(Kt + (size_t)(mt * 16 + lm) * DKH + kk * 32 + g * 8);

        // S^T = K * Q^T
        floatx4 sacc[4][4];
#pragma unroll
        for (int mt = 0; mt < 4; ++mt)
#pragma unroll
            for (int nt = 0; nt < 4; ++nt) { floatx4 z = {0.f, 0.f, 0.f, 0.f}; sacc[mt][nt] = z; }
#pragma unroll
        for (int kk = 0; kk < 2; ++kk)
#pragma unroll
            for (int mt = 0; mt < 4; ++mt)
#pragma unroll
                for (int nt = 0; nt < 4; ++nt)
                    sacc[mt][nt] = __builtin_amdgcn_mfma_f32_16x16x32_bf16(kf[mt][kk], qf[nt][kk], sacc[mt][nt], 0, 0, 0);

        // V^T tile as A-frags (issued here; latency hidden under exp)
        bf16x8 vf[4][2];
#pragma unroll
        for (int dt = 0; dt < 4; ++dt)
#pragma unroll
            for (int kk = 0; kk < 2; ++kk)
                vf[dt][kk] = *(const bf16x8*)(Vtt + (size_t)(dt * 16 + lm) * SEQ + kk * 32 + g * 8);

        // exp2 + pack + wave-private P write (b64, swizzled)
#pragma unroll
        for (int mt = 0; mt < 4; ++mt)
#pragma unroll
            for (int nt = 0; nt < 4; ++nt) {
                bf16x4 pk = {(bf16_t)__builtin_amdgcn_exp2f(sacc[mt][nt][0]),
                             (bf16_t)__builtin_amdgcn_exp2f(sacc[mt][nt][1]),
                             (bf16_t)__builtin_amdgcn_exp2f(sacc[mt][nt][2]),
                             (bf16_t)__builtin_amdgcn_exp2f(sacc[mt][nt][3])};
                *(bf16x4*)&Ps[w][(nt * 16 + lm) * 64 + (((mt * 4 + g) ^ xsw) << 2)] = pk;
            }

        // O^T += V^T * P^T ; lsum via ones-MFMA
#pragma unroll
        for (int kk = 0; kk < 2; ++kk) {
            bf16x8 bp[4];
#pragma unroll
            for (int nt = 0; nt < 4; ++nt)
                bp[nt] = *(const bf16x8*)&Ps[w][(nt * 16 + lm) * 64 + (((kk * 8 + g * 2) ^ xsw) << 2)];
#pragma unroll
            for (int nt = 0; nt < 4; ++nt)
                lacc[nt] = __builtin_amdgcn_mfma_f32_16x16x32_bf16(onesf, bp[nt], lacc[nt], 0, 0, 0);
#pragma unroll
            for (int dt = 0; dt < 4; ++dt)
#pragma unroll
                for (int nt = 0; nt < 4; ++nt)
                    oacc[dt][nt] = __builtin_amdgcn_mfma_f32_16x16x32_bf16(vf[dt][kk], bp[nt], oacc[dt][nt], 0, 0, 0);
        }
    }

    // merge key-split partials (2 dt-passes through 18 KB fp32 LDS)
    float linv[4];
#pragma unroll
    for (int pass = 0; pass < 2; ++pass) {
        __syncthreads();
        if (ks == 1) {
#pragma unroll
            for (int dh = 0; dh < 2; ++dh) {
                int dt = pass * 2 + dh;
#pragma unroll
                for (int nt = 0; nt < 4; ++nt)
                    *(floatx4*)&Ms[qw][(nt * 16 + lm) * 36 + dh * 16 + g * 4] = oacc[dt][nt];
            }
            if (pass == 0 && g == 0)
#pragma unroll
                for (int nt = 0; nt < 4; ++nt)
                    Ms[qw][(nt * 16 + lm) * 36 + 32] = lacc[nt][0];
        }
        __syncthreads();
        if (ks == 0) {
            if (pass == 0)
#pragma unroll
                for (int nt = 0; nt < 4; ++nt)
                    linv[nt] = 1.0f / (lacc[nt][0] + Ms[qw][(nt * 16 + lm) * 36 + 32]);
#pragma unroll
            for (int dh = 0; dh < 2; ++dh) {
                int dt = pass * 2 + dh;
#pragma unroll
                for (int nt = 0; nt < 4; ++nt) {
                    floatx4 part = *(const floatx4*)&Ms[qw][(nt * 16 + lm) * 36 + dh * 16 + g * 4];
                    bf16x4 pk = {(bf16_t)((oacc[dt][nt][0] + part[0]) * linv[nt]),
                                 (bf16_t)((oacc[dt][nt][1] + part[1]) * linv[nt]),
                                 (bf16_t)((oacc[dt][nt][2] + part[2]) * linv[nt]),
                                 (bf16_t)((oacc[dt][nt][3] + part[3]) * linv[nt])};
                    int q = q0 + nt * 16 + lm;
                    int d = h * DKH + dt * 16 + g * 4;
                    *(bf16x4*)&Cc[((size_t)(b * SEQ + q)) * DMODEL + d] = pk;
                }
            }
        }
    }
}

// ----------------------------------------------------------------------------
extern "C" void kernel_launch(void* const* d_in, const int* in_sizes, int n_in,
                              void* d_out, int out_size, void* d_ws, size_t ws_size,
                              hipStream_t stream) {
    const float* x  = (const float*)d_in[0];
    const float* Wq = (const float*)d_in[1];
    const float* Wk = (const float*)d_in[2];
    const float* Wv = (const float*)d_in[3];
    const float* Wo = (const float*)d_in[4];

    const size_t NX = (size_t)MROWS * DMODEL;
    const size_t NW = (size_t)DMODEL * DMODEL;
    bf16_t* ws  = (bf16_t*)d_ws;
    bf16_t* xb  = ws;            // x bf16
    bf16_t* Wt  = xb + NX;       // W^T x4 contiguous: q,k,v,o
    bf16_t* Wto = Wt + 3 * NW;
    bf16_t* Qb  = Wt + 4 * NW;   // (b,h,s,d), scaled by log2(e)/8
    bf16_t* Kb  = Qb + NX;       // (b,h,s,d)
    bf16_t* Vtb = Kb + NX;       // (b,h,d,s)
    bf16_t* Cc  = Vtb + NX;      // concat

    cast_x_kernel<<<NX / 1024, 256, 0, stream>>>(x, xb);
    transpose4_kernel<<<dim3(32, 32, 4), dim3(32, 8), 0, stream>>>(Wq, Wk, Wv, Wo, Wt);

    gemm128_kernel<0><<<dim3(3 * DMODEL / 128, MROWS / 128), 256, 0, stream>>>(xb, Wt, Qb);

    attn_kernel<<<dim3(BATCH * NHEADS, SEQ / 128), 256, 0, stream>>>(Qb, Kb, Vtb, Cc);

    gemm128_kernel<3><<<dim3(DMODEL / 128, MROWS / 128), 256, 0, stream>>>(Cc, Wto, (float*)d_out);
}

// Round 5
// 197.912 us; speedup vs baseline: 1.0467x; 1.0467x over previous
//
#include <hip/hip_runtime.h>
#include <hip/hip_bf16.h>
#include <math.h>

#define DMODEL 1024
#define NHEADS 16
#define DKH    64
#define BATCH  2
#define SEQ    2048
#define MROWS  (BATCH * SEQ)   // 4096
#define LOG2E  1.4426950408889634f

typedef __bf16 bf16_t;
typedef bf16_t bf16x8 __attribute__((ext_vector_type(8)));
typedef bf16_t bf16x4 __attribute__((ext_vector_type(4)));
typedef float  floatx4 __attribute__((ext_vector_type(4)));

// async global->LDS, 16B per lane
__device__ __forceinline__ void glds16(const bf16_t* g, bf16_t* l) {
    __builtin_amdgcn_global_load_lds((__attribute__((address_space(1))) unsigned*)(g),
                                     (__attribute__((address_space(3))) unsigned*)(l),
                                     16, 0, 0);
}

// ---------------------------------------------------------------- cast x -> bf16
__global__ void cast_x_kernel(const float* __restrict__ x, bf16_t* __restrict__ xb) {
    int i = (blockIdx.x * 256 + threadIdx.x) * 4;
    float4 v = *(const float4*)(x + i);
    bf16_t o0 = (bf16_t)v.x, o1 = (bf16_t)v.y, o2 = (bf16_t)v.z, o3 = (bf16_t)v.w;
    bf16_t o[4] = {o0, o1, o2, o3};
    *(uint2*)(xb + i) = *(uint2*)o;
}

// --------------------------- 4x W (K x N) -> W^T (N x K) bf16, fused over z
__global__ void transpose4_kernel(const float* __restrict__ W0, const float* __restrict__ W1,
                                  const float* __restrict__ W2, const float* __restrict__ W3,
                                  bf16_t* __restrict__ Wt) {
    __shared__ float t[32][33];
    const float* W = (blockIdx.z == 0) ? W0 : (blockIdx.z == 1) ? W1 : (blockIdx.z == 2) ? W2 : W3;
    bf16_t* dst = Wt + (size_t)blockIdx.z * DMODEL * DMODEL;
    int bx = blockIdx.x, by = blockIdx.y;
    int tx = threadIdx.x, ty = threadIdx.y;
#pragma unroll
    for (int i = 0; i < 32; i += 8)
        t[ty + i][tx] = W[(size_t)(by * 32 + ty + i) * DMODEL + bx * 32 + tx];
    __syncthreads();
#pragma unroll
    for (int i = 0; i < 32; i += 8)
        dst[(size_t)(bx * 32 + ty + i) * DMODEL + by * 32 + tx] = (bf16_t)t[tx][ty + i];
}

// ---------------------------------------------------------------- 128x128 GEMM, BK=64
// MODE 0: fused QKV epilogue. Q -> (b,h,s,d) scaled; K,V -> FRAG-MAJOR layout:
//   frag buffer elem addr = ((bh*32 + kt)*8 + sub)*512 + lane*8 + j
//   K: sub = mt*2+kk, lane = gK*16+lmK  (gK,jK from d; mt,lmK from s)
//   V: sub = dt*2+kkV, lane = gV*16+lmV (dt,lmV from d; kkV,gV,jV from s)
// MODE 3: fp32 row-major (final output)
template<int MODE>
__global__ __launch_bounds__(256) void gemm128_kernel(const bf16_t* __restrict__ A,
                                                      const bf16_t* __restrict__ Bt,
                                                      void* __restrict__ outp) {
    __shared__ bf16_t As[128 * 64];
    __shared__ bf16_t Bs[128 * 64];
    int tid = threadIdx.x;
    int w = tid >> 6, l = tid & 63, g = l >> 4, lm = l & 15;
    int wr = w >> 1, wc = w & 1;
    int m0 = blockIdx.y * 128, n0 = blockIdx.x * 128;
    int r8 = l >> 3, s8 = l & 7, cw = s8 ^ r8;

    floatx4 acc[4][4];
#pragma unroll
    for (int i = 0; i < 4; ++i)
#pragma unroll
        for (int j = 0; j < 4; ++j) { floatx4 z = {0.f, 0.f, 0.f, 0.f}; acc[i][j] = z; }

    const bf16_t* Ag = A  + (size_t)(m0 + w * 32 + r8) * DMODEL + cw * 8;
    const bf16_t* Bg = Bt + (size_t)(n0 + w * 32 + r8) * DMODEL + cw * 8;

    for (int k0 = 0; k0 < DMODEL; k0 += 64) {
        __syncthreads();
#pragma unroll
        for (int j = 0; j < 4; ++j) {
            glds16(Ag + (size_t)j * 8 * DMODEL + k0, &As[(w * 32 + j * 8) * 64]);
            glds16(Bg + (size_t)j * 8 * DMODEL + k0, &Bs[(w * 32 + j * 8) * 64]);
        }
        __syncthreads();
#pragma unroll
        for (int kk = 0; kk < 2; ++kk) {
            bf16x8 af[4], bfr[4];
            int c = kk * 4 + g;
            int sw = (c ^ (lm & 7)) * 8;
#pragma unroll
            for (int i = 0; i < 4; ++i) {
                af[i]  = *(const bf16x8*)&As[(wr * 64 + i * 16 + lm) * 64 + sw];
                bfr[i] = *(const bf16x8*)&Bs[(wc * 64 + i * 16 + lm) * 64 + sw];
            }
#pragma unroll
            for (int i = 0; i < 4; ++i)
#pragma unroll
                for (int j = 0; j < 4; ++j)
                    acc[i][j] = __builtin_amdgcn_mfma_f32_16x16x32_bf16(af[i], bfr[j], acc[i][j], 0, 0, 0);
        }
    }

    const size_t NX = (size_t)MROWS * DMODEL;
#pragma unroll
    for (int i = 0; i < 4; ++i) {
#pragma unroll
        for (int j = 0; j < 4; ++j) {
            int nc = n0 + wc * 64 + j * 16 + lm;
            int mb = m0 + wr * 64 + i * 16 + g * 4;
            if (MODE == 0) {
                int mat = n0 >> 10;              // block-uniform
                int col = nc & 1023;
                int hh = col >> 6, d = col & 63;
                int b = mb >> 11;
                int bh2 = b * NHEADS + hh;
                int s0 = mb & 2047;
                int kt = s0 >> 6;
                bf16_t* base = (bf16_t*)outp;
                if (mat == 0) {                  // Q (b,h,s,d), scaled log2(e)/8
#pragma unroll
                    for (int r = 0; r < 4; ++r)
                        base[((size_t)bh2 * SEQ + s0 + r) * DKH + d] = (bf16_t)(acc[i][j][r] * (0.125f * LOG2E));
                } else if (mat == 1) {           // K frag-major
                    int kk = d >> 5, gK = (d >> 3) & 3, jK = d & 7;
                    int rt = s0 & 63, mt = rt >> 4, lmK = rt & 15;
                    bf16_t* Kfb = base + NX;
                    size_t tb = (((size_t)bh2 * 32 + kt) * 8 + mt * 2 + kk) * 512 + (gK * 16 + lmK) * 8 + jK;
#pragma unroll
                    for (int r = 0; r < 4; ++r)
                        Kfb[tb + (size_t)r * 8] = (bf16_t)acc[i][j][r];
                } else {                         // V frag-major (from V^T view)
                    int dt = d >> 4, lmV = d & 15;
                    int s63 = s0 & 63;
                    int kkV = s63 >> 5, gV = (s63 >> 3) & 3, jV = s63 & 7;
                    bf16_t* Vfb = base + 2 * NX;
                    size_t tb = (((size_t)bh2 * 32 + kt) * 8 + dt * 2 + kkV) * 512 + (gV * 16 + lmV) * 8 + jV;
                    bf16x4 pk = {(bf16_t)acc[i][j][0], (bf16_t)acc[i][j][1],
                                 (bf16_t)acc[i][j][2], (bf16_t)acc[i][j][3]};
                    *(bf16x4*)&Vfb[tb] = pk;
                }
            } else {
#pragma unroll
                for (int r = 0; r < 4; ++r)
                    ((float*)outp)[(size_t)(mb + r) * DMODEL + nc] = acc[i][j][r];
            }
        }
    }
}

// ---------------------------------------------------------------- fused flash attention
// grid (32 bh, 16 qblk), block 256 = 4 waves = 2 q-groups x 2 key-splits.
// K/V in frag-major layout: every frag load = base + lane*16B, fully coalesced 1KB.
// K double-buffered in regs (prefetch kt+1 under exp). No barriers in K-loop.
// P round-trips wave-private LDS (swizzled). Merge buffer aliases P LDS (32 KB total).
__global__ __launch_bounds__(256, 2) void attn_kernel(const bf16_t* __restrict__ Q,
                                                      const bf16_t* __restrict__ Kf,
                                                      const bf16_t* __restrict__ Vf,
                                                      bf16_t* __restrict__ Cc) {
    __shared__ __align__(16) char smem[32768];
    bf16_t* Ps = (bf16_t*)smem;          // [w][4096] wave-private P tile
    float*  Ms = (float*)smem;           // merge: [(qw*64+q)*36 + ...] (aliased, used after loop)

    int tid = threadIdx.x;
    int w = tid >> 6, l = tid & 63, g = l >> 4, lm = l & 15;
    int qw = w & 1, ks = w >> 1;
    int bh = blockIdx.x, b = bh >> 4, h = bh & 15;
    int q0 = blockIdx.y * 128 + qw * 64;
    int xsw = lm & 14;

    const bf16_t* Qh  = Q  + ((size_t)bh * SEQ + q0) * DKH;
    const bf16_t* Kfh = Kf + (size_t)bh * 32 * 8 * 512 + l * 8;
    const bf16_t* Vfh = Vf + (size_t)bh * 32 * 8 * 512 + l * 8;

    // Q as B-frags (loaded once)
    bf16x8 qf[4][2];
#pragma unroll
    for (int nt = 0; nt < 4; ++nt)
#pragma unroll
        for (int kk = 0; kk < 2; ++kk)
            qf[nt][kk] = *(const bf16x8*)(Qh + (size_t)(nt * 16 + lm) * DKH + kk * 32 + g * 8);

    floatx4 oacc[4][4];
#pragma unroll
    for (int dt = 0; dt < 4; ++dt)
#pragma unroll
        for (int nt = 0; nt < 4; ++nt) { floatx4 z = {0.f, 0.f, 0.f, 0.f}; oacc[dt][nt] = z; }
    float lsum[4] = {0.f, 0.f, 0.f, 0.f};

    int kt0 = ks * 16;
    bf16x8 kf[4][2], kfn[4][2], vf[4][2];
#pragma unroll
    for (int mt = 0; mt < 4; ++mt)
#pragma unroll
        for (int kk = 0; kk < 2; ++kk)
            kf[mt][kk] = *(const bf16x8*)(Kfh + ((size_t)kt0 * 8 + mt * 2 + kk) * 512);

#pragma unroll 2
    for (int it = 0; it < 16; ++it) {
        int kt = kt0 + it;
        const bf16_t* Vt = Vfh + (size_t)kt * 8 * 512;

        // V frags for this iter (consumed at the end, latency hidden under S+exp)
#pragma unroll
        for (int dt = 0; dt < 4; ++dt)
#pragma unroll
            for (int kk = 0; kk < 2; ++kk)
                vf[dt][kk] = *(const bf16x8*)(Vt + (dt * 2 + kk) * 512);

        // S^T = K * Q^T
        floatx4 sacc[4][4];
#pragma unroll
        for (int mt = 0; mt < 4; ++mt)
#pragma unroll
            for (int nt = 0; nt < 4; ++nt) { floatx4 z = {0.f, 0.f, 0.f, 0.f}; sacc[mt][nt] = z; }
#pragma unroll
        for (int kk = 0; kk < 2; ++kk)
#pragma unroll
            for (int mt = 0; mt < 4; ++mt)
#pragma unroll
                for (int nt = 0; nt < 4; ++nt)
                    sacc[mt][nt] = __builtin_amdgcn_mfma_f32_16x16x32_bf16(kf[mt][kk], qf[nt][kk], sacc[mt][nt], 0, 0, 0);

        // prefetch next iter's K frags (ready long before next S)
        int ktn = (it < 15) ? kt + 1 : kt0;
        const bf16_t* Kn = Kfh + (size_t)ktn * 8 * 512;
#pragma unroll
        for (int mt = 0; mt < 4; ++mt)
#pragma unroll
            for (int kk = 0; kk < 2; ++kk)
                kfn[mt][kk] = *(const bf16x8*)(Kn + (mt * 2 + kk) * 512);

        // exp2 + lsum + packed b64 P write (wave-private, swizzled)
#pragma unroll
        for (int mt = 0; mt < 4; ++mt)
#pragma unroll
            for (int nt = 0; nt < 4; ++nt) {
                float p0 = __builtin_amdgcn_exp2f(sacc[mt][nt][0]);
                float p1 = __builtin_amdgcn_exp2f(sacc[mt][nt][1]);
                float p2 = __builtin_amdgcn_exp2f(sacc[mt][nt][2]);
                float p3 = __builtin_amdgcn_exp2f(sacc[mt][nt][3]);
                lsum[nt] += (p0 + p1) + (p2 + p3);
                bf16x4 pk = {(bf16_t)p0, (bf16_t)p1, (bf16_t)p2, (bf16_t)p3};
                *(bf16x4*)&Ps[w * 4096 + (nt * 16 + lm) * 64 + (((mt * 4 + g) ^ xsw) << 2)] = pk;
            }

        // O^T += V^T * P^T (same-wave LDS, in-order DS pipe)
#pragma unroll
        for (int kk = 0; kk < 2; ++kk) {
            bf16x8 bp[4];
#pragma unroll
            for (int nt = 0; nt < 4; ++nt)
                bp[nt] = *(const bf16x8*)&Ps[w * 4096 + (nt * 16 + lm) * 64 + (((kk * 8 + g * 2) ^ xsw) << 2)];
#pragma unroll
            for (int dt = 0; dt < 4; ++dt)
#pragma unroll
                for (int nt = 0; nt < 4; ++nt)
                    oacc[dt][nt] = __builtin_amdgcn_mfma_f32_16x16x32_bf16(vf[dt][kk], bp[nt], oacc[dt][nt], 0, 0, 0);
        }

        // rotate K double-buffer
#pragma unroll
        for (int mt = 0; mt < 4; ++mt)
#pragma unroll
            for (int kk = 0; kk < 2; ++kk)
                kf[mt][kk] = kfn[mt][kk];
    }

    // reduce lsum across the 4 g-groups (lanes ^16, ^32)
#pragma unroll
    for (int nt = 0; nt < 4; ++nt) {
        float s = lsum[nt];
        s += __shfl_xor(s, 16, 64);
        s += __shfl_xor(s, 32, 64);
        lsum[nt] = s;
    }

    // merge key-split partials (2 dt-passes; Ms aliases the dead P LDS)
    float linv[4];
#pragma unroll
    for (int pass = 0; pass < 2; ++pass) {
        __syncthreads();
        if (ks == 1) {
#pragma unroll
            for (int dh = 0; dh < 2; ++dh) {
                int dt = pass * 2 + dh;
#pragma unroll
                for (int nt = 0; nt < 4; ++nt)
                    *(floatx4*)&Ms[(qw * 64 + nt * 16 + lm) * 36 + dh * 16 + g * 4] = oacc[dt][nt];
            }
            if (pass == 0 && g == 0)
#pragma unroll
                for (int nt = 0; nt < 4; ++nt)
                    Ms[(qw * 64 + nt * 16 + lm) * 36 + 32] = lsum[nt];
        }
        __syncthreads();
        if (ks == 0) {
            if (pass == 0)
#pragma unroll
                for (int nt = 0; nt < 4; ++nt)
                    linv[nt] = 1.0f / (lsum[nt] + Ms[(qw * 64 + nt * 16 + lm) * 36 + 32]);
#pragma unroll
            for (int dh = 0; dh < 2; ++dh) {
                int dt = pass * 2 + dh;
#pragma unroll
                for (int nt = 0; nt < 4; ++nt) {
                    floatx4 part = *(const floatx4*)&Ms[(qw * 64 + nt * 16 + lm) * 36 + dh * 16 + g * 4];
                    bf16x4 pk = {(bf16_t)((oacc[dt][nt][0] + part[0]) * linv[nt]),
                                 (bf16_t)((oacc[dt][nt][1] + part[1]) * linv[nt]),
                                 (bf16_t)((oacc[dt][nt][2] + part[2]) * linv[nt]),
                                 (bf16_t)((oacc[dt][nt][3] + part[3]) * linv[nt])};
                    int q = q0 + nt * 16 + lm;
                    int d = h * DKH + dt * 16 + g * 4;
                    *(bf16x4*)&Cc[((size_t)(b * SEQ + q)) * DMODEL + d] = pk;
                }
            }
        }
    }
}

// ----------------------------------------------------------------------------
extern "C" void kernel_launch(void* const* d_in, const int* in_sizes, int n_in,
                              void* d_out, int out_size, void* d_ws, size_t ws_size,
                              hipStream_t stream) {
    const float* x  = (const float*)d_in[0];
    const float* Wq = (const float*)d_in[1];
    const float* Wk = (const float*)d_in[2];
    const float* Wv = (const float*)d_in[3];
    const float* Wo = (const float*)d_in[4];

    const size_t NX = (size_t)MROWS * DMODEL;
    const size_t NW = (size_t)DMODEL * DMODEL;
    bf16_t* ws  = (bf16_t*)d_ws;
    bf16_t* xb  = ws;            // x bf16
    bf16_t* Wt  = xb + NX;       // W^T x4 contiguous: q,k,v,o
    bf16_t* Wto = Wt + 3 * NW;
    bf16_t* Qb  = Wt + 4 * NW;   // Q (b,h,s,d), scaled log2(e)/8
    bf16_t* Kfb = Qb + NX;       // K frag-major
    bf16_t* Vfb = Kfb + NX;      // V frag-major
    bf16_t* Cc  = Vfb + NX;      // concat

    cast_x_kernel<<<NX / 1024, 256, 0, stream>>>(x, xb);
    transpose4_kernel<<<dim3(32, 32, 4), dim3(32, 8), 0, stream>>>(Wq, Wk, Wv, Wo, Wt);

    gemm128_kernel<0><<<dim3(3 * DMODEL / 128, MROWS / 128), 256, 0, stream>>>(xb, Wt, Qb);

    attn_kernel<<<dim3(BATCH * NHEADS, SEQ / 128), 256, 0, stream>>>(Qb, Kfb, Vfb, Cc);

    gemm128_kernel<3><<<dim3(DMODEL / 128, MROWS / 128), 256, 0, stream>>>(Cc, Wto, (float*)d_out);
}